// Round 3
// baseline (73.474 us; speedup 1.0000x reference)
//
#include <hip/hip_runtime.h>
#include <hip/hip_cooperative_groups.h>

namespace cg = cooperative_groups;

static constexpr int NPIX = 256 * 256;
static constexpr int NBLK = 256;
static constexpr int ROWS_PER_BLK = 27;          // 6912 rows / 256 blocks
static constexpr int F4_PER_BLK = ROWS_PER_BLK * 192;  // 5184

typedef float f4 __attribute__((ext_vector_type(4)));

// v6 = relu(relu(3*v2)+3) — monotone non-decreasing in v2 (as are v8, v21).
__device__ __forceinline__ float chain_v6(float v2) {
    return fmaxf(fmaxf(3.0f * v2, 0.0f) + 3.0f, 0.0f);
}
__device__ __forceinline__ float chain_v21(float v2) {
    float t = 3.0f * chain_v6(v2);
    t = fmaxf(t - 3.0f, 0.0f);
    t = fmaxf(t - 3.0f, 0.0f);
    t = fmaxf(t - 3.0f, 0.0f);
    return t - 6.0f;
}

__global__ __launch_bounds__(256) void k_fused(const float* __restrict__ x,
                                               const float* __restrict__ Wp,
                                               const float* __restrict__ bp,
                                               float* __restrict__ M,
                                               float2* __restrict__ partials,
                                               f4* __restrict__ out) {
    const int t = threadIdx.x;
    const int blk = blockIdx.x;
    const int p = blk * 256 + t;  // pixel index, 0..65535
    const int lane = t & 63, wid = t >> 6;

    float W[9];
#pragma unroll
    for (int i = 0; i < 9; ++i) W[i] = Wp[i];  // W[i*3+o], torch (in,out) layout
    const float bias[3] = {bp[0], bp[1], bp[2]};

    // ---- phase 1: per-pixel batch-max M, per-block max/min of v2 ----
    float Mc[3] = {-3.4e38f, -3.4e38f, -3.4e38f};
    float minv2 = 3.4e38f;

#pragma unroll
    for (int b = 0; b < 6; ++b) {
        const float x0 = x[(b * 3 + 0) * NPIX + p];
        const float x1 = x[(b * 3 + 1) * NPIX + p];
        const float x2 = x[(b * 3 + 2) * NPIX + p];
#pragma unroll
        for (int c = 0; c < 3; ++c) {
            float v2 = fmaf(x0, W[c], fmaf(x1, W[3 + c], fmaf(x2, W[6 + c], bias[c] + 3.0f)));
            Mc[c] = fmaxf(Mc[c], v2);
            minv2 = fminf(minv2, v2);
        }
    }

    M[0 * NPIX + p] = Mc[0];
    M[1 * NPIX + p] = Mc[1];
    M[2 * NPIX + p] = Mc[2];

    float maxv2 = fmaxf(Mc[0], fmaxf(Mc[1], Mc[2]));
#pragma unroll
    for (int o = 32; o > 0; o >>= 1) {
        maxv2 = fmaxf(maxv2, __shfl_down(maxv2, o));
        minv2 = fminf(minv2, __shfl_down(minv2, o));
    }
    __shared__ float smx[4], smn[4];
    if (lane == 0) { smx[wid] = maxv2; smn[wid] = minv2; }
    __syncthreads();
    if (t == 0) {
        float a = fmaxf(fmaxf(smx[0], smx[1]), fmaxf(smx[2], smx[3]));
        float bmn = fminf(fminf(smn[0], smn[1]), fminf(smn[2], smn[3]));
        partials[blk] = make_float2(a, bmn);  // plain store, no init needed
    }
    __threadfence();
    cg::this_grid().sync();
    __threadfence();

    // ---- phase 2: every block reduces the 256 partials, then writes rows ----
    float2 pr = partials[t];  // 256 threads read 256 float2, coalesced, L2-hot
    float A = pr.x, B = pr.y;
#pragma unroll
    for (int o = 32; o > 0; o >>= 1) {
        A = fmaxf(A, __shfl_down(A, o));
        B = fminf(B, __shfl_down(B, o));
    }
    __shared__ float sA[4], sB[4];
    __syncthreads();
    if (lane == 0) { sA[wid] = A; sB[wid] = B; }
    __syncthreads();
    const float Ag = fmaxf(fmaxf(sA[0], sA[1]), fmaxf(sA[2], sA[3]));
    const float Bg = fminf(fminf(sB[0], sB[1]), fminf(sB[2], sB[3]));

    // out = m1 + max(v2) + 2*min(v6) + max(v8) + min(v21)
    const float S = Ag + 2.0f * chain_v6(Bg) + (3.0f * chain_v6(Ag) + 3.0f) + chain_v21(Bg);

    const f4* __restrict__ Mv = (const f4*)M;
    const int base_f4 = blk * F4_PER_BLK;  // block's 27 rows are contiguous
#pragma unroll 1
    for (int j = t; j < F4_PER_BLK; j += 256) {
        const int rl = j / 192;                    // local row 0..26
        const int w4 = j - rl * 192;               // f4 index within row
        const int row = blk * ROWS_PER_BLK + rl;   // global row = xr*9 + k
        const int c = row % 3;                     // (row%9)%3 == row%3
        const int xr = (row / 9) & 255;
        f4 m = Mv[c * (NPIX / 4) + xr * 64 + (w4 & 63)];
        __builtin_nontemporal_store(m + S, &out[base_f4 + j]);
    }
}

extern "C" void kernel_launch(void* const* d_in, const int* in_sizes, int n_in,
                              void* d_out, int out_size, void* d_ws, size_t ws_size,
                              hipStream_t stream) {
    const float* x = (const float*)d_in[0];   // [6,3,256,256]
    const float* W = (const float*)d_in[1];   // [3,3] (in,out)
    const float* b = (const float*)d_in[2];   // [3]
    f4* out = (f4*)d_out;                     // [768,9,768]

    float* M = (float*)d_ws;                                      // 3*65536 floats
    float2* partials = (float2*)((char*)d_ws + 3 * NPIX * 4);     // 256 float2

    void* args[] = {(void*)&x, (void*)&W, (void*)&b, (void*)&M, (void*)&partials, (void*)&out};
    hipLaunchCooperativeKernel((const void*)k_fused, dim3(NBLK), dim3(256), args, 0, stream);
}

// Round 4
// 15.321 us; speedup vs baseline: 4.7958x; 4.7958x over previous
//
#include <hip/hip_runtime.h>

static constexpr int NPIX = 256 * 256;

typedef float f4 __attribute__((ext_vector_type(4)));

// v6 = relu(relu(3*v2)+3) — monotone non-decreasing in v2 (as are v8, v21),
// so global min/max of the chained values are the chains applied to min/max(v2).
__device__ __forceinline__ float chain_v6(float v2) {
    return fmaxf(fmaxf(3.0f * v2, 0.0f) + 3.0f, 0.0f);
}
__device__ __forceinline__ float chain_v21(float v2) {
    float t = 3.0f * chain_v6(v2);
    t = fmaxf(t - 3.0f, 0.0f);
    t = fmaxf(t - 3.0f, 0.0f);
    t = fmaxf(t - 3.0f, 0.0f);
    return t - 6.0f;
}

// k1: one thread per pixel. Writes per-pixel batch-max M[3][65536] and
// per-block (max v2, min v2) partials via plain stores (no init needed).
__global__ __launch_bounds__(256) void k_compute(const float* __restrict__ x,
                                                 const float* __restrict__ Wp,
                                                 const float* __restrict__ bp,
                                                 float* __restrict__ M,
                                                 float2* __restrict__ partials) {
    const int t = threadIdx.x;
    const int p = blockIdx.x * 256 + t;
    const int lane = t & 63, wid = t >> 6;

    float W[9];
#pragma unroll
    for (int i = 0; i < 9; ++i) W[i] = Wp[i];  // torch (in,out) layout
    const float bias[3] = {bp[0], bp[1], bp[2]};

    float Mc[3] = {-3.4e38f, -3.4e38f, -3.4e38f};
    float minv2 = 3.4e38f;

#pragma unroll
    for (int b = 0; b < 6; ++b) {
        const float x0 = x[(b * 3 + 0) * NPIX + p];
        const float x1 = x[(b * 3 + 1) * NPIX + p];
        const float x2 = x[(b * 3 + 2) * NPIX + p];
#pragma unroll
        for (int c = 0; c < 3; ++c) {
            float v2 = fmaf(x0, W[c], fmaf(x1, W[3 + c], fmaf(x2, W[6 + c], bias[c] + 3.0f)));
            Mc[c] = fmaxf(Mc[c], v2);
            minv2 = fminf(minv2, v2);
        }
    }

    M[0 * NPIX + p] = Mc[0];
    M[1 * NPIX + p] = Mc[1];
    M[2 * NPIX + p] = Mc[2];

    float maxv2 = fmaxf(Mc[0], fmaxf(Mc[1], Mc[2]));
#pragma unroll
    for (int o = 32; o > 0; o >>= 1) {
        maxv2 = fmaxf(maxv2, __shfl_down(maxv2, o));
        minv2 = fminf(minv2, __shfl_down(minv2, o));
    }
    __shared__ float smx[4], smn[4];
    if (lane == 0) { smx[wid] = maxv2; smn[wid] = minv2; }
    __syncthreads();
    if (t == 0) {
        partials[blockIdx.x] =
            make_float2(fmaxf(fmaxf(smx[0], smx[1]), fmaxf(smx[2], smx[3])),
                        fminf(fminf(smn[0], smn[1]), fminf(smn[2], smn[3])));
    }
}

// k2: 648 blocks x 256 threads, 8 float4/thread (648*2048 = 1,327,104 f4).
// Each block redundantly reduces the 256 partials (L2-hot, ~0.25us) -> S,
// then streams a contiguous 32KB slice: out[j] = M[c, xr, :] + S.
__global__ __launch_bounds__(256) void k_out(const f4* __restrict__ Mv,
                                             const float2* __restrict__ partials,
                                             f4* __restrict__ out) {
    const int t = threadIdx.x;
    const int lane = t & 63, wid = t >> 6;

    float2 pr = partials[t];
    float A = pr.x, B = pr.y;
#pragma unroll
    for (int o = 32; o > 0; o >>= 1) {
        A = fmaxf(A, __shfl_down(A, o));
        B = fminf(B, __shfl_down(B, o));
    }
    __shared__ float sA[4], sB[4];
    if (lane == 0) { sA[wid] = A; sB[wid] = B; }
    __syncthreads();
    const float Ag = fmaxf(fmaxf(sA[0], sA[1]), fmaxf(sA[2], sA[3]));
    const float Bg = fminf(fminf(sB[0], sB[1]), fminf(sB[2], sB[3]));
    // out = m1 + max(v2) + 2*min(v6) + max(v8) + min(v21)
    const float S = Ag + 2.0f * chain_v6(Bg) + (3.0f * chain_v6(Ag) + 3.0f) + chain_v21(Bg);

    const int jbase = blockIdx.x * 2048 + t;
#pragma unroll
    for (int i = 0; i < 8; ++i) {
        const int j = jbase + i * 256;            // global f4 index
        const int row = j / 192;                  // output row = xr*9 + k
        const int w4 = j - row * 192;             // f4 within row
        const int c = row % 3;                    // (row%9)%3 == row%3
        const int xr = (row / 9) & 255;
        f4 m = Mv[c * (NPIX / 4) + xr * 64 + (w4 & 63)];
        __builtin_nontemporal_store(m + S, &out[j]);
    }
}

extern "C" void kernel_launch(void* const* d_in, const int* in_sizes, int n_in,
                              void* d_out, int out_size, void* d_ws, size_t ws_size,
                              hipStream_t stream) {
    const float* x = (const float*)d_in[0];   // [6,3,256,256]
    const float* W = (const float*)d_in[1];   // [3,3] (in,out)
    const float* b = (const float*)d_in[2];   // [3]

    float* M = (float*)d_ws;                                    // 3*65536 floats
    float2* partials = (float2*)((char*)d_ws + 3 * NPIX * 4);   // 256 float2

    hipLaunchKernelGGL(k_compute, dim3(NPIX / 256), dim3(256), 0, stream, x, W, b, M, partials);
    hipLaunchKernelGGL(k_out, dim3(648), dim3(256), 0, stream, (const f4*)M, partials, (f4*)d_out);
}

// Round 5
// 15.082 us; speedup vs baseline: 4.8717x; 1.0158x over previous
//
#include <hip/hip_runtime.h>

static constexpr int NPIX = 256 * 256;

typedef float f4 __attribute__((ext_vector_type(4)));

// v6 = relu(relu(3*v2)+3) — monotone non-decreasing in v2 (as are v8, v21),
// so global min/max of the chained values are the chains applied to min/max(v2).
__device__ __forceinline__ float chain_v6(float v2) {
    return fmaxf(fmaxf(3.0f * v2, 0.0f) + 3.0f, 0.0f);
}
__device__ __forceinline__ float chain_v21(float v2) {
    float t = 3.0f * chain_v6(v2);
    t = fmaxf(t - 3.0f, 0.0f);
    t = fmaxf(t - 3.0f, 0.0f);
    t = fmaxf(t - 3.0f, 0.0f);
    return t - 6.0f;
}

// k1: one thread per pixel. Writes per-pixel batch-max M[3][65536] and
// per-block (max v2, min v2) partials via plain stores (no init needed).
// Non-temporal x loads: x is read exactly once; keep L2 for M.
__global__ __launch_bounds__(256) void k_compute(const float* __restrict__ x,
                                                 const float* __restrict__ Wp,
                                                 const float* __restrict__ bp,
                                                 float* __restrict__ M,
                                                 float2* __restrict__ partials) {
    const int t = threadIdx.x;
    const int p = blockIdx.x * 256 + t;
    const int lane = t & 63, wid = t >> 6;

    float W[9];
#pragma unroll
    for (int i = 0; i < 9; ++i) W[i] = Wp[i];  // torch (in,out) layout
    const float bias[3] = {bp[0], bp[1], bp[2]};

    float Mc[3] = {-3.4e38f, -3.4e38f, -3.4e38f};
    float minv2 = 3.4e38f;

#pragma unroll
    for (int b = 0; b < 6; ++b) {
        const float x0 = __builtin_nontemporal_load(&x[(b * 3 + 0) * NPIX + p]);
        const float x1 = __builtin_nontemporal_load(&x[(b * 3 + 1) * NPIX + p]);
        const float x2 = __builtin_nontemporal_load(&x[(b * 3 + 2) * NPIX + p]);
#pragma unroll
        for (int c = 0; c < 3; ++c) {
            float v2 = fmaf(x0, W[c], fmaf(x1, W[3 + c], fmaf(x2, W[6 + c], bias[c] + 3.0f)));
            Mc[c] = fmaxf(Mc[c], v2);
            minv2 = fminf(minv2, v2);
        }
    }

    M[0 * NPIX + p] = Mc[0];
    M[1 * NPIX + p] = Mc[1];
    M[2 * NPIX + p] = Mc[2];

    float maxv2 = fmaxf(Mc[0], fmaxf(Mc[1], Mc[2]));
#pragma unroll
    for (int o = 32; o > 0; o >>= 1) {
        maxv2 = fmaxf(maxv2, __shfl_down(maxv2, o));
        minv2 = fminf(minv2, __shfl_down(minv2, o));
    }
    __shared__ float smx[4], smn[4];
    if (lane == 0) { smx[wid] = maxv2; smn[wid] = minv2; }
    __syncthreads();
    if (t == 0) {
        partials[blockIdx.x] =
            make_float2(fmaxf(fmaxf(smx[0], smx[1]), fmaxf(smx[2], smx[3])),
                        fminf(fminf(smn[0], smn[1]), fminf(smn[2], smn[3])));
    }
}

// k2: grid (3, 768) x 192 threads. Block (c, xr) loads one f4 of M[c, xr%256, :]
// per thread and stores it (+S) to output rows k = c, c+3, c+6 of row-group xr.
// Zero per-element address math; 1 L2 load + 3 contiguous NT stores per thread.
__global__ __launch_bounds__(192) void k_out(const f4* __restrict__ Mv,
                                             const float2* __restrict__ partials,
                                             f4* __restrict__ out) {
    const int t = threadIdx.x;
    const int lane = t & 63, wid = t >> 6;

    // redundant per-block reduce of the 256 partials (L2-hot)
    float2 pr = partials[t];
    float A = pr.x, B = pr.y;
    if (t < 64) {
        float2 q = partials[192 + t];
        A = fmaxf(A, q.x);
        B = fminf(B, q.y);
    }
#pragma unroll
    for (int o = 32; o > 0; o >>= 1) {
        A = fmaxf(A, __shfl_down(A, o));
        B = fminf(B, __shfl_down(B, o));
    }
    __shared__ float sA[3], sB[3];
    if (lane == 0) { sA[wid] = A; sB[wid] = B; }
    __syncthreads();
    const float Ag = fmaxf(sA[0], fmaxf(sA[1], sA[2]));
    const float Bg = fminf(sB[0], fminf(sB[1], sB[2]));
    // out = m1 + max(v2) + 2*min(v6) + max(v8) + min(v21)
    const float S = Ag + 2.0f * chain_v6(Bg) + (3.0f * chain_v6(Ag) + 3.0f) + chain_v21(Bg);

    const int c = blockIdx.x;   // 0..2
    const int xr = blockIdx.y;  // 0..767

    const f4 m = Mv[c * (NPIX / 4) + (xr & 255) * 64 + (t & 63)];
    const f4 r = m + S;
    const int base = (xr * 9 + c) * 192 + t;
    __builtin_nontemporal_store(r, &out[base]);           // k = c
    __builtin_nontemporal_store(r, &out[base + 576]);     // k = c+3
    __builtin_nontemporal_store(r, &out[base + 1152]);    // k = c+6
}

extern "C" void kernel_launch(void* const* d_in, const int* in_sizes, int n_in,
                              void* d_out, int out_size, void* d_ws, size_t ws_size,
                              hipStream_t stream) {
    const float* x = (const float*)d_in[0];   // [6,3,256,256]
    const float* W = (const float*)d_in[1];   // [3,3] (in,out)
    const float* b = (const float*)d_in[2];   // [3]

    float* M = (float*)d_ws;                                    // 3*65536 floats
    float2* partials = (float2*)((char*)d_ws + 3 * NPIX * 4);   // 256 float2

    hipLaunchKernelGGL(k_compute, dim3(NPIX / 256), dim3(256), 0, stream, x, W, b, M, partials);
    hipLaunchKernelGGL(k_out, dim3(3, 768), dim3(192), 0, stream, (const f4*)M, partials, (f4*)d_out);
}